// Round 2
// baseline (1043.417 us; speedup 1.0000x reference)
//
#include <hip/hip_runtime.h>
#include <hip/hip_bf16.h>
#include <math.h>

// Problem constants (fixed by setup_inputs)
#define B_  2
#define NH  4
#define HH  64
#define WW  64
#define KD  32
#define L_  4096            // HH*WW
#define BN_ 8               // B_*NH
#define SCALE 0.17677669529663687f   // 1/sqrt(32)

// ---------------------------------------------------------------------------
// Kernel A: qkv = x @ w_qkv  (M=8192, K=128, N=384), scatter into q/k/v
// layouts [b][head][l][32]. K is pre-scaled by 1/sqrt(32) (only used in QK).
// ---------------------------------------------------------------------------
__global__ __launch_bounds__(256) void qkv_gemm(const float* __restrict__ x,
                                                const float* __restrict__ w,
                                                float* __restrict__ q_ws,
                                                float* __restrict__ k_ws,
                                                float* __restrict__ v_ws) {
    __shared__ float As[64][68];
    __shared__ float Bs[64][68];
    const int mt = blockIdx.x % 128;
    const int nt = blockIdx.x / 128;
    const int m0 = mt * 64, n0 = nt * 64;
    const int tid = threadIdx.x;
    const int ti = tid / 16, tj = tid % 16;
    float acc[4][4] = {};

    for (int k0 = 0; k0 < 128; k0 += 64) {
        #pragma unroll
        for (int i = 0; i < 16; i++) {
            int e = i * 256 + tid;
            int row = e >> 6, col = e & 63;
            As[row][col] = x[(m0 + row) * 128 + k0 + col];
        }
        #pragma unroll
        for (int i = 0; i < 16; i++) {
            int e = i * 256 + tid;
            int kk = e >> 6, col = e & 63;
            Bs[kk][col] = w[(k0 + kk) * 384 + n0 + col];
        }
        __syncthreads();
        #pragma unroll 8
        for (int kk = 0; kk < 64; kk++) {
            float av[4];
            #pragma unroll
            for (int r = 0; r < 4; r++) av[r] = As[ti * 4 + r][kk];
            const float4 b4 = *(const float4*)&Bs[kk][tj * 4];
            const float bv[4] = {b4.x, b4.y, b4.z, b4.w};
            #pragma unroll
            for (int r = 0; r < 4; r++)
                #pragma unroll
                for (int c = 0; c < 4; c++)
                    acc[r][c] = fmaf(av[r], bv[c], acc[r][c]);
        }
        __syncthreads();
    }

    const int which = n0 >> 7;                 // 0=q, 1=k, 2=v
    float* dst = (which == 0) ? q_ws : (which == 1) ? k_ws : v_ws;
    const float mult = (which == 1) ? SCALE : 1.0f;
    const int nc = n0 & 127;
    #pragma unroll
    for (int r = 0; r < 4; r++) {
        const int m = m0 + ti * 4 + r;
        const int b = m >> 12, l = m & 4095;
        #pragma unroll
        for (int c = 0; c < 4; c++) {
            const int col = nc + tj * 4 + c;
            const int hd = col >> 5, d = col & 31;
            dst[((b * NH + hd) * L_ + l) * KD + d] = acc[r][c] * mult;
        }
    }
}

// ---------------------------------------------------------------------------
// Kernel B: absolute-indexed relative bias tables.
//   qw_abs[bn][w2][w1][h1] = dot(q[bn,h1,w1,:], emb_w[w2-w1+63,:])
//   qh_abs[bn][h2][w1][h1] = dot(q[bn,h1,w1,:], emb_h[h2-h1+63,:])
// ---------------------------------------------------------------------------
__global__ __launch_bounds__(256) void bias_tables(const float* __restrict__ q_ws,
                                                   const float* __restrict__ emb_h,
                                                   const float* __restrict__ emb_w,
                                                   float* __restrict__ qw_abs,
                                                   float* __restrict__ qh_abs) {
    __shared__ float qs[64][33];
    __shared__ float ehs[127][33];
    __shared__ float ews[127][33];
    const int bn = blockIdx.x >> 6;
    const int w1 = blockIdx.x & 63;
    const int tid = threadIdx.x;

    #pragma unroll
    for (int i = 0; i < 8; i++) {
        int e = i * 256 + tid;
        int h1 = e >> 5, d = e & 31;
        qs[h1][d] = q_ws[(bn * L_ + h1 * 64 + w1) * KD + d];
    }
    #pragma unroll
    for (int i = 0; i < 16; i++) {
        int e = i * 256 + tid;
        if (e < 127 * 32) {
            int r = e >> 5, d = e & 31;
            ehs[r][d] = emb_h[e];
            ews[r][d] = emb_w[e];
        }
    }
    __syncthreads();

    const int h1 = tid & 63;
    const int mg = tid >> 6;
    for (int mm = 0; mm < 16; mm++) {
        const int m2 = mg * 16 + mm;
        const float* qrow = &qs[h1][0];
        const float* erw  = &ews[m2 - w1 + 63][0];
        const float* erh  = &ehs[m2 - h1 + 63][0];
        float sw = 0.f, sh = 0.f;
        #pragma unroll
        for (int d = 0; d < 32; d++) {
            sw = fmaf(qrow[d], erw[d], sw);
            sh = fmaf(qrow[d], erh[d], sh);
        }
        const int oidx = bn * (64 * L_) + m2 * L_ + w1 * 64 + h1;
        qw_abs[oidx] = sw;
        qh_abs[oidx] = sh;
    }
}

// ---------------------------------------------------------------------------
// Kernel C: flash attention. Block = (bn, w1): 8 waves x 64 lanes (512 thr).
// lane = h1 (query), wave = key-split (8 rows of h2 each). Online softmax
// per lane with 4-way partial QK sums (short dep chains) + 2-key unroll;
// merge the 8 splits through LDS; write [B,H,W,C] output.
// LDS 70 KB -> 2 blocks/CU -> 16 waves/CU; launch_bounds caps VGPR at 128.
// ---------------------------------------------------------------------------
__global__ __launch_bounds__(512, 4) void attn(const float* __restrict__ q_ws,
                                               const float* __restrict__ k_ws,
                                               const float* __restrict__ v_ws,
                                               const float* __restrict__ qw_abs,
                                               const float* __restrict__ qh_abs,
                                               float* __restrict__ out) {
    __shared__ float lds_acc[8][64][33];
    __shared__ float lds_m[8][64];
    __shared__ float lds_l[8][64];
    const int bn = blockIdx.x >> 6;
    const int w1 = blockIdx.x & 63;
    const int sp = threadIdx.x >> 6;     // key split 0..7
    const int lane = threadIdx.x & 63;   // h1

    float4 q4[8];
    const float4* qp = (const float4*)&q_ws[(bn * L_ + lane * 64 + w1) * KD];
    #pragma unroll
    for (int j = 0; j < 8; j++) q4[j] = qp[j];

    float m = -INFINITY, l = 0.f;
    float4 a4[8];
    #pragma unroll
    for (int j = 0; j < 8; j++) a4[j] = make_float4(0.f, 0.f, 0.f, 0.f);

    const float* qwb = qw_abs + bn * (64 * L_) + w1 * 64 + lane;
    const float* qhb = qh_abs + bn * (64 * L_) + w1 * 64 + lane;

    for (int h2 = sp * 8; h2 < sp * 8 + 8; h2++) {
        const float bh = qhb[h2 * L_];                        // coalesced
        const float4* krow = (const float4*)&k_ws[(bn * L_ + h2 * 64) * KD];
        const float4* vrow = (const float4*)&v_ws[(bn * L_ + h2 * 64) * KD];
        for (int w2 = 0; w2 < 64; w2 += 2) {
            const float bw0 = qwb[w2 * L_];                   // coalesced
            const float bw1 = qwb[(w2 + 1) * L_];
            const float4* kp0 = krow + w2 * 8;                // broadcast loads
            const float4* kp1 = kp0 + 8;
            // 4-way partial sums per key: dep chain 8 FMAs instead of 32
            float s0p[4] = {0.f, 0.f, 0.f, 0.f};
            float s1p[4] = {0.f, 0.f, 0.f, 0.f};
            #pragma unroll
            for (int j = 0; j < 8; j++) {
                const float4 kv0 = kp0[j];
                const int pj = j & 3;
                s0p[pj] = fmaf(q4[j].x, kv0.x, s0p[pj]);
                s0p[pj] = fmaf(q4[j].y, kv0.y, s0p[pj]);
                s0p[pj] = fmaf(q4[j].z, kv0.z, s0p[pj]);
                s0p[pj] = fmaf(q4[j].w, kv0.w, s0p[pj]);
            }
            #pragma unroll
            for (int j = 0; j < 8; j++) {
                const float4 kv1 = kp1[j];
                const int pj = j & 3;
                s1p[pj] = fmaf(q4[j].x, kv1.x, s1p[pj]);
                s1p[pj] = fmaf(q4[j].y, kv1.y, s1p[pj]);
                s1p[pj] = fmaf(q4[j].z, kv1.z, s1p[pj]);
                s1p[pj] = fmaf(q4[j].w, kv1.w, s1p[pj]);
            }
            const float s0 = ((s0p[0] + s0p[1]) + (s0p[2] + s0p[3])) + (bh + bw0);
            const float s1 = ((s1p[0] + s1p[1]) + (s1p[2] + s1p[3])) + (bh + bw1);
            const float mn = fmaxf(m, fmaxf(s0, s1));
            if (mn > m) {                                     // rare after warm-up
                const float alpha = __expf(m - mn);           // exp(-inf)=0 handles init
                m = mn;
                l *= alpha;
                #pragma unroll
                for (int j = 0; j < 8; j++) {
                    a4[j].x *= alpha; a4[j].y *= alpha;
                    a4[j].z *= alpha; a4[j].w *= alpha;
                }
            }
            const float p0 = __expf(s0 - m);
            const float p1 = __expf(s1 - m);
            l += p0 + p1;
            const float4* vp0 = vrow + w2 * 8;                // broadcast loads
            const float4* vp1 = vp0 + 8;
            #pragma unroll
            for (int j = 0; j < 8; j++) {
                const float4 vv0 = vp0[j];
                const float4 vv1 = vp1[j];
                a4[j].x = fmaf(p0, vv0.x, fmaf(p1, vv1.x, a4[j].x));
                a4[j].y = fmaf(p0, vv0.y, fmaf(p1, vv1.y, a4[j].y));
                a4[j].z = fmaf(p0, vv0.z, fmaf(p1, vv1.z, a4[j].z));
                a4[j].w = fmaf(p0, vv0.w, fmaf(p1, vv1.w, a4[j].w));
            }
        }
    }

    // dump per-split partials
    #pragma unroll
    for (int j = 0; j < 8; j++) {
        lds_acc[sp][lane][4 * j + 0] = a4[j].x;
        lds_acc[sp][lane][4 * j + 1] = a4[j].y;
        lds_acc[sp][lane][4 * j + 2] = a4[j].z;
        lds_acc[sp][lane][4 * j + 3] = a4[j].w;
    }
    lds_m[sp][lane] = m;
    lds_l[sp][lane] = l;
    __syncthreads();

    // merge: thread = (h1, eighth of d-range), 512 threads cover 64x32/4
    const int h1 = threadIdx.x >> 3;
    const int dg = threadIdx.x & 7;
    float M = -INFINITY;
    #pragma unroll
    for (int s = 0; s < 8; s++) M = fmaxf(M, lds_m[s][h1]);
    float e[8];
    float denom = 0.f;
    #pragma unroll
    for (int s = 0; s < 8; s++) {
        e[s] = __expf(lds_m[s][h1] - M);
        denom = fmaf(e[s], lds_l[s][h1], denom);
    }
    const float inv = 1.0f / denom;
    const int b = bn >> 2, n = bn & 3;
    float* op = &out[((b * HH + h1) * WW + w1) * 128 + n * KD + dg * 4];
    float4 o4;
    float o[4];
    #pragma unroll
    for (int j = 0; j < 4; j++) {
        const int d = dg * 4 + j;
        float acc = 0.f;
        #pragma unroll
        for (int s = 0; s < 8; s++) acc = fmaf(e[s], lds_acc[s][h1][d], acc);
        o[j] = acc * inv;
    }
    o4.x = o[0]; o4.y = o[1]; o4.z = o[2]; o4.w = o[3];
    *(float4*)op = o4;
}

// ---------------------------------------------------------------------------
extern "C" void kernel_launch(void* const* d_in, const int* in_sizes, int n_in,
                              void* d_out, int out_size, void* d_ws, size_t ws_size,
                              hipStream_t stream) {
    const float* x     = (const float*)d_in[0];   // [2,64,64,128]
    const float* w_qkv = (const float*)d_in[1];   // [128,384]
    const float* emb_h = (const float*)d_in[2];   // [127,32]
    const float* emb_w = (const float*)d_in[3];   // [127,32]
    float* out = (float*)d_out;

    // workspace layout (floats): q,k,v 1M each; qw_abs,qh_abs 2M each = 28 MB
    float* q_ws   = (float*)d_ws;
    float* k_ws   = q_ws + (size_t)BN_ * L_ * KD;
    float* v_ws   = k_ws + (size_t)BN_ * L_ * KD;
    float* qw_abs = v_ws + (size_t)BN_ * L_ * KD;
    float* qh_abs = qw_abs + (size_t)BN_ * 64 * L_;

    qkv_gemm<<<768, 256, 0, stream>>>(x, w_qkv, q_ws, k_ws, v_ws);
    bias_tables<<<512, 256, 0, stream>>>(q_ws, emb_h, emb_w, qw_abs, qh_abs);
    attn<<<512, 512, 0, stream>>>(q_ws, k_ws, v_ws, qw_abs, qh_abs, out);
}

// Round 3
// 233.604 us; speedup vs baseline: 4.4666x; 4.4666x over previous
//
#include <hip/hip_runtime.h>
#include <hip/hip_bf16.h>
#include <math.h>

// Problem constants (fixed by setup_inputs)
#define B_  2
#define NH  4
#define HH  64
#define WW  64
#define KD  32
#define L_  4096            // HH*WW
#define BN_ 8               // B_*NH
#define SCALE 0.17677669529663687f   // 1/sqrt(32)

// MFMA fragment types (guide §3: 8 bf16 in 4 VGPRs, 4 fp32 acc)
typedef short bfrag  __attribute__((ext_vector_type(8), may_alias));
typedef float f32x4  __attribute__((ext_vector_type(4), may_alias));

__device__ __forceinline__ unsigned short f2bf(float f) {
    __hip_bfloat16 h = __float2bfloat16(f);
    return *(unsigned short*)&h;
}

// ---------------------------------------------------------------------------
// Kernel A: qkv = x @ w_qkv  (M=8192, K=128, N=384).
// Outputs: q_f32 [bn][l][32] (for bias tables), q_bf/k_bf [bn][l][32] bf16
// (k pre-scaled by 1/sqrt(32)), vt_bf [bn][32][l] bf16 (V transposed).
// ---------------------------------------------------------------------------
__global__ __launch_bounds__(256) void qkv_gemm(const float* __restrict__ x,
                                                const float* __restrict__ w,
                                                float* __restrict__ q_f32,
                                                unsigned short* __restrict__ q_bf,
                                                unsigned short* __restrict__ k_bf,
                                                unsigned short* __restrict__ vt_bf) {
    __shared__ float As[64][68];
    __shared__ float Bs[64][68];
    const int mt = blockIdx.x % 128;
    const int nt = blockIdx.x / 128;
    const int m0 = mt * 64, n0 = nt * 64;
    const int tid = threadIdx.x;
    const int ti = tid / 16, tj = tid % 16;
    float acc[4][4] = {};

    for (int k0 = 0; k0 < 128; k0 += 64) {
        #pragma unroll
        for (int i = 0; i < 16; i++) {
            int e = i * 256 + tid;
            int row = e >> 6, col = e & 63;
            As[row][col] = x[(m0 + row) * 128 + k0 + col];
        }
        #pragma unroll
        for (int i = 0; i < 16; i++) {
            int e = i * 256 + tid;
            int kk = e >> 6, col = e & 63;
            Bs[kk][col] = w[(k0 + kk) * 384 + n0 + col];
        }
        __syncthreads();
        #pragma unroll 8
        for (int kk = 0; kk < 64; kk++) {
            float av[4];
            #pragma unroll
            for (int r = 0; r < 4; r++) av[r] = As[ti * 4 + r][kk];
            const float4 b4 = *(const float4*)&Bs[kk][tj * 4];
            const float bv[4] = {b4.x, b4.y, b4.z, b4.w};
            #pragma unroll
            for (int r = 0; r < 4; r++)
                #pragma unroll
                for (int c = 0; c < 4; c++)
                    acc[r][c] = fmaf(av[r], bv[c], acc[r][c]);
        }
        __syncthreads();
    }

    const int which = n0 >> 7;                 // 0=q, 1=k, 2=v
    const int nc = n0 & 127;
    #pragma unroll
    for (int r = 0; r < 4; r++) {
        const int m = m0 + ti * 4 + r;
        const int b = m >> 12, l = m & 4095;
        #pragma unroll
        for (int c = 0; c < 4; c++) {
            const int col = nc + tj * 4 + c;
            const int hd = col >> 5, d = col & 31;
            const int bn = b * NH + hd;
            const float v = acc[r][c];
            if (which == 0) {
                q_f32[((size_t)bn * L_ + l) * 32 + d] = v;
                q_bf [((size_t)bn * L_ + l) * 32 + d] = f2bf(v);
            } else if (which == 1) {
                k_bf [((size_t)bn * L_ + l) * 32 + d] = f2bf(v * SCALE);
            } else {
                vt_bf[((size_t)bn * 32 + d) * L_ + l] = f2bf(v);
            }
        }
    }
}

// ---------------------------------------------------------------------------
// Kernel B: absolute-indexed relative bias tables (fp32).
//   qw_abs[bn][w2][w1][h1] = dot(q[bn,h1,w1,:], emb_w[w2-w1+63,:])
//   qh_abs[bn][h2][w1][h1] = dot(q[bn,h1,w1,:], emb_h[h2-h1+63,:])
// ---------------------------------------------------------------------------
__global__ __launch_bounds__(256) void bias_tables(const float* __restrict__ q_f32,
                                                   const float* __restrict__ emb_h,
                                                   const float* __restrict__ emb_w,
                                                   float* __restrict__ qw_abs,
                                                   float* __restrict__ qh_abs) {
    __shared__ float qs[64][33];
    __shared__ float ehs[127][33];
    __shared__ float ews[127][33];
    const int bn = blockIdx.x >> 6;
    const int w1 = blockIdx.x & 63;
    const int tid = threadIdx.x;

    #pragma unroll
    for (int i = 0; i < 8; i++) {
        int e = i * 256 + tid;
        int h1 = e >> 5, d = e & 31;
        qs[h1][d] = q_f32[((size_t)bn * L_ + h1 * 64 + w1) * 32 + d];
    }
    #pragma unroll
    for (int i = 0; i < 16; i++) {
        int e = i * 256 + tid;
        if (e < 127 * 32) {
            int r = e >> 5, d = e & 31;
            ehs[r][d] = emb_h[e];
            ews[r][d] = emb_w[e];
        }
    }
    __syncthreads();

    const int h1 = tid & 63;
    const int mg = tid >> 6;
    for (int mm = 0; mm < 16; mm++) {
        const int m2 = mg * 16 + mm;
        const float* qrow = &qs[h1][0];
        const float* erw  = &ews[m2 - w1 + 63][0];
        const float* erh  = &ehs[m2 - h1 + 63][0];
        float sw = 0.f, sh = 0.f;
        #pragma unroll
        for (int d = 0; d < 32; d++) {
            sw = fmaf(qrow[d], erw[d], sw);
            sh = fmaf(qrow[d], erh[d], sh);
        }
        const size_t oidx = (size_t)bn * (64 * L_) + (size_t)m2 * L_ + w1 * 64 + h1;
        qw_abs[oidx] = sw;
        qh_abs[oidx] = sh;
    }
}

// ---------------------------------------------------------------------------
// Kernel C: MFMA flash attention.
// Block = (bn, w1), 256 threads = 4 waves. Wave wv owns queries h1 in
// [16wv, 16wv+16). Key-tile = 64 keys = one full h2 row (h2 = kt).
// QK^T: S(16q x 64k) = 4x mfma_16x16x32(aq, bk, bias-as-C).
// Online softmax in C-layout (row=q=quad*4+reg, col=key=lane&15).
// P -> bf16 -> per-wave LDS -> A-frags; PV: O(16q x 32d) += 4x mfma.
// K/Vt tiles double-buffered, register-prefetch staging, XOR chunk swizzle
// so all ds_read_b128 land <=2-way bank conflicts (free, m136).
// ---------------------------------------------------------------------------
__global__ __launch_bounds__(256) void attn_mfma(
    const unsigned short* __restrict__ q_bf,   // [bn][l][32]
    const unsigned short* __restrict__ k_bf,   // [bn][l][32], pre-scaled
    const unsigned short* __restrict__ vt_bf,  // [bn][32][l]
    const float* __restrict__ qw_abs,          // [bn][w2][w1][h1]
    const float* __restrict__ qh_abs,          // [bn][h2][w1][h1]
    float* __restrict__ out)
{
    __shared__ bfrag    Kbuf[2][256];     // 64 rows x 4 chunks(16B), swizzled: 8KB
    __shared__ bfrag    Vtbuf[2][256];    // 32 rows x 8 chunks, swizzled: 8KB
    __shared__ f32x4    qh_lds[64 * 18];  // [h2][q], row=72 floats (16 data +2 pad f32x4)
    __shared__ f32x4    qw_lds[64 * 18];  // [w2][q]
    __shared__ unsigned P_lds[4][16 * 36];// per-wave P[16q][72bf16-row]

    const int bn   = blockIdx.x >> 6;
    const int w1   = blockIdx.x & 63;
    const int tid  = threadIdx.x;
    const int wv   = tid >> 6;
    const int lane = tid & 63;
    const int l16  = lane & 15;
    const int quad = lane >> 4;
    const int q0   = wv * 16;

    // ---- stage bias strips for this (bn, w1): 2 x 64x64 fp32 ----
    #pragma unroll
    for (int i = 0; i < 4; i++) {
        int e = i * 256 + tid;             // 0..1023 f32x4 slots
        int row = e >> 4, c4 = e & 15;
        const size_t g = ((size_t)bn * 64 + row) * L_ + w1 * 64 + c4 * 4;
        qh_lds[row * 18 + c4] = *(const f32x4*)&qh_abs[g];
        qw_lds[row * 18 + c4] = *(const f32x4*)&qw_abs[g];
    }

    // ---- Q fragment (A-operand): lane holds Q[q0+l16][quad*8..+8) ----
    const int qg = q0 + l16;               // h1
    const bfrag aq = *(const bfrag*)(q_bf + (((size_t)bn * L_ + qg * 64 + w1) * 32 + quad * 8));

    // ---- staging thread->global mapping (XOR chunk swizzle) ----
    const int sKr = tid >> 2, sKs = tid & 3, sKc = sKs ^ ((sKr >> 1) & 3);
    const unsigned short* gK = k_bf + (((size_t)bn * L_ + sKr) * 32 + sKc * 8);
    const int sVd = tid >> 3, sVs = tid & 7, sVc = sVs ^ (sVd & 7);
    const unsigned short* gV = vt_bf + ((size_t)(bn * 32 + sVd)) * L_ + sVc * 8;
    bfrag rK = *(const bfrag*)gK;
    bfrag rV = *(const bfrag*)gV;

    const int kswz = quad ^ ((l16 >> 1) & 3);      // K b_frag chunk slot

    f32x4 O0 = {0.f, 0.f, 0.f, 0.f}, O1 = {0.f, 0.f, 0.f, 0.f};
    float m_[4], l_[4];
    #pragma unroll
    for (int r = 0; r < 4; r++) { m_[r] = -INFINITY; l_[r] = 0.f; }

    for (int kt = 0; kt < 64; kt++) {
        const int bsel = kt & 1;
        // write staged tile, prefetch next
        Kbuf[bsel][tid]  = rK;
        Vtbuf[bsel][tid] = rV;
        if (kt < 63) {
            rK = *(const bfrag*)(gK + (size_t)(kt + 1) * 64 * 32);
            rV = *(const bfrag*)(gV + (kt + 1) * 64);
        }
        __syncthreads();

        // ---- QK^T with bias as C-init ----
        const f32x4 qh4 = qh_lds[kt * 18 + wv * 4 + quad];   // broadcast (h2 = kt)
        f32x4 S[4];
        #pragma unroll
        for (int sub = 0; sub < 4; sub++) {
            const f32x4 qw4 = qw_lds[(sub * 16 + l16) * 18 + wv * 4 + quad];
            const f32x4 cinit = qh4 + qw4;
            const bfrag bk = Kbuf[bsel][sub * 64 + l16 * 4 + kswz];
            S[sub] = __builtin_amdgcn_mfma_f32_16x16x32_bf16(aq, bk, cinit, 0, 0, 0);
        }

        // ---- online softmax (rows = queries, reduce over 16 lanes + 4 subs) ----
        float mx[4];
        #pragma unroll
        for (int r = 0; r < 4; r++)
            mx[r] = fmaxf(fmaxf(S[0][r], S[1][r]), fmaxf(S[2][r], S[3][r]));
        #pragma unroll
        for (int st = 1; st < 16; st <<= 1)
            #pragma unroll
            for (int r = 0; r < 4; r++)
                mx[r] = fmaxf(mx[r], __shfl_xor(mx[r], st));
        float alpha[4];
        #pragma unroll
        for (int r = 0; r < 4; r++) {
            const float mn = fmaxf(m_[r], mx[r]);
            alpha[r] = __expf(m_[r] - mn);      // exp(-inf)=0 on first tile
            m_[r] = mn;
        }
        float p[4][4], ls[4] = {0.f, 0.f, 0.f, 0.f};
        #pragma unroll
        for (int sub = 0; sub < 4; sub++)
            #pragma unroll
            for (int r = 0; r < 4; r++) {
                p[sub][r] = __expf(S[sub][r] - m_[r]);
                ls[r] += p[sub][r];
            }
        #pragma unroll
        for (int st = 1; st < 16; st <<= 1)
            #pragma unroll
            for (int r = 0; r < 4; r++)
                ls[r] += __shfl_xor(ls[r], st);
        #pragma unroll
        for (int r = 0; r < 4; r++) {
            l_[r] = l_[r] * alpha[r] + ls[r];
            O0[r] *= alpha[r];
            O1[r] *= alpha[r];
        }

        // ---- P (bf16) -> per-wave LDS, packed pairs along key ----
        unsigned* Pw = P_lds[wv];
        #pragma unroll
        for (int sub = 0; sub < 4; sub++)
            #pragma unroll
            for (int r = 0; r < 4; r++) {
                const float v = p[sub][r];
                const float o = __shfl_xor(v, 1);
                if (!(lane & 1)) {
                    __hip_bfloat162 pk = __float22bfloat162_rn(make_float2(v, o));
                    Pw[(quad * 4 + r) * 36 + ((sub * 16 + l16) >> 1)] = *(unsigned*)&pk;
                }
            }

        // ---- PV: O(16q x 32d) += P(16q x 64k) * V(64k x 32d) ----
        const unsigned short* Pus = (const unsigned short*)Pw;
        const bfrag pa0 = *(const bfrag*)(Pus + l16 * 72 + quad * 8);        // keys 0..31
        const bfrag pa1 = *(const bfrag*)(Pus + l16 * 72 + 32 + quad * 8);   // keys 32..63
        {
            const int d0 = l16;                       // d half 0
            const int sa = quad       ^ (d0 & 7);     // chunk for keys quad*8..
            const int sb = (quad + 4) ^ (d0 & 7);     // chunk for keys 32+quad*8..
            const bfrag bv0 = Vtbuf[bsel][d0 * 8 + sa];
            const bfrag bv1 = Vtbuf[bsel][d0 * 8 + sb];
            O0 = __builtin_amdgcn_mfma_f32_16x16x32_bf16(pa0, bv0, O0, 0, 0, 0);
            O0 = __builtin_amdgcn_mfma_f32_16x16x32_bf16(pa1, bv1, O0, 0, 0, 0);
            const int d1 = 16 + l16;                  // d half 1 ((d1&7)==(d0&7))
            const bfrag bv2 = Vtbuf[bsel][d1 * 8 + sa];
            const bfrag bv3 = Vtbuf[bsel][d1 * 8 + sb];
            O1 = __builtin_amdgcn_mfma_f32_16x16x32_bf16(pa0, bv2, O1, 0, 0, 0);
            O1 = __builtin_amdgcn_mfma_f32_16x16x32_bf16(pa1, bv3, O1, 0, 0, 0);
        }
        // single barrier per iter is sufficient with 2 buffers (see analysis)
    }

    // ---- epilogue: out[b][h1][w1][head*32 + d] ----
    const int head = bn & 3, bb = bn >> 2;
    #pragma unroll
    for (int r = 0; r < 4; r++) {
        const float inv = 1.0f / l_[r];
        const int q = q0 + quad * 4 + r;     // h1
        const size_t oi = (((size_t)bb * 64 + q) * 64 + w1) * 128 + head * 32;
        out[oi + l16]      = O0[r] * inv;
        out[oi + 16 + l16] = O1[r] * inv;
    }
}

// ---------------------------------------------------------------------------
extern "C" void kernel_launch(void* const* d_in, const int* in_sizes, int n_in,
                              void* d_out, int out_size, void* d_ws, size_t ws_size,
                              hipStream_t stream) {
    const float* x     = (const float*)d_in[0];   // [2,64,64,128]
    const float* w_qkv = (const float*)d_in[1];   // [128,384]
    const float* emb_h = (const float*)d_in[2];   // [127,32]
    const float* emb_w = (const float*)d_in[3];   // [127,32]
    float* out = (float*)d_out;

    // workspace: q_f32 (1M f), qw_abs (2M f), qh_abs (2M f), then bf16:
    // q_bf, k_bf (1M ush each), vt_bf (1M ush) -> 26 MB total
    float* q_f32  = (float*)d_ws;
    float* qw_abs = q_f32 + (size_t)BN_ * L_ * KD;
    float* qh_abs = qw_abs + (size_t)BN_ * 64 * L_;
    unsigned short* q_bf  = (unsigned short*)(qh_abs + (size_t)BN_ * 64 * L_);
    unsigned short* k_bf  = q_bf + (size_t)BN_ * L_ * KD;
    unsigned short* vt_bf = k_bf + (size_t)BN_ * L_ * KD;

    qkv_gemm<<<768, 256, 0, stream>>>(x, w_qkv, q_f32, q_bf, k_bf, vt_bf);
    bias_tables<<<512, 256, 0, stream>>>(q_f32, emb_h, emb_w, qw_abs, qh_abs);
    attn_mfma<<<512, 256, 0, stream>>>(q_bf, k_bf, vt_bf, qw_abs, qh_abs, out);
}

// Round 4
// 184.794 us; speedup vs baseline: 5.6464x; 1.2641x over previous
//
#include <hip/hip_runtime.h>
#include <hip/hip_bf16.h>
#include <math.h>

// Problem constants (fixed by setup_inputs)
#define B_  2
#define NH  4
#define HH  64
#define WW  64
#define KD  32
#define L_  4096            // HH*WW
#define BN_ 8               // B_*NH
#define SCALE 0.17677669529663687f   // 1/sqrt(32)
#define MARGIN 3.0f

// MFMA fragment types (guide §3: 8 bf16 in 4 VGPRs, 4 fp32 acc)
typedef short bfrag  __attribute__((ext_vector_type(8), may_alias));
typedef float f32x4  __attribute__((ext_vector_type(4), may_alias));

__device__ __forceinline__ unsigned short f2bf(float f) {
    __hip_bfloat16 h = __float2bfloat16(f);
    return *(unsigned short*)&h;
}

// ---------------------------------------------------------------------------
// Kernel A: qkv = x @ w_qkv  (M=8192, K=128, N=384).
// Outputs: q_f32 [bn][l][32] (for bias tables), q_bf/k_bf [bn][l][32] bf16
// (k pre-scaled by 1/sqrt(32)), vt_bf [bn][32][l] bf16 (V transposed).
// ---------------------------------------------------------------------------
__global__ __launch_bounds__(256) void qkv_gemm(const float* __restrict__ x,
                                                const float* __restrict__ w,
                                                float* __restrict__ q_f32,
                                                unsigned short* __restrict__ q_bf,
                                                unsigned short* __restrict__ k_bf,
                                                unsigned short* __restrict__ vt_bf) {
    __shared__ float As[64][68];
    __shared__ float Bs[64][68];
    const int mt = blockIdx.x % 128;
    const int nt = blockIdx.x / 128;
    const int m0 = mt * 64, n0 = nt * 64;
    const int tid = threadIdx.x;
    const int ti = tid / 16, tj = tid % 16;
    float acc[4][4] = {};

    for (int k0 = 0; k0 < 128; k0 += 64) {
        #pragma unroll
        for (int i = 0; i < 16; i++) {
            int e = i * 256 + tid;
            int row = e >> 6, col = e & 63;
            As[row][col] = x[(m0 + row) * 128 + k0 + col];
        }
        #pragma unroll
        for (int i = 0; i < 16; i++) {
            int e = i * 256 + tid;
            int kk = e >> 6, col = e & 63;
            Bs[kk][col] = w[(k0 + kk) * 384 + n0 + col];
        }
        __syncthreads();
        #pragma unroll 8
        for (int kk = 0; kk < 64; kk++) {
            float av[4];
            #pragma unroll
            for (int r = 0; r < 4; r++) av[r] = As[ti * 4 + r][kk];
            const float4 b4 = *(const float4*)&Bs[kk][tj * 4];
            const float bv[4] = {b4.x, b4.y, b4.z, b4.w};
            #pragma unroll
            for (int r = 0; r < 4; r++)
                #pragma unroll
                for (int c = 0; c < 4; c++)
                    acc[r][c] = fmaf(av[r], bv[c], acc[r][c]);
        }
        __syncthreads();
    }

    const int which = n0 >> 7;                 // 0=q, 1=k, 2=v
    const int nc = n0 & 127;
    #pragma unroll
    for (int r = 0; r < 4; r++) {
        const int m = m0 + ti * 4 + r;
        const int b = m >> 12, l = m & 4095;
        #pragma unroll
        for (int c = 0; c < 4; c++) {
            const int col = nc + tj * 4 + c;
            const int hd = col >> 5, d = col & 31;
            const int bn = b * NH + hd;
            const float v = acc[r][c];
            if (which == 0) {
                q_f32[((size_t)bn * L_ + l) * 32 + d] = v;
                q_bf [((size_t)bn * L_ + l) * 32 + d] = f2bf(v);
            } else if (which == 1) {
                k_bf [((size_t)bn * L_ + l) * 32 + d] = f2bf(v * SCALE);
            } else {
                vt_bf[((size_t)bn * 32 + d) * L_ + l] = f2bf(v);
            }
        }
    }
}

// ---------------------------------------------------------------------------
// Kernel B: absolute-indexed relative bias tables (fp32).
//   qw_abs[bn][w2][w1][h1] = dot(q[bn,h1,w1,:], emb_w[w2-w1+63,:])
//   qh_abs[bn][h2][w1][h1] = dot(q[bn,h1,w1,:], emb_h[h2-h1+63,:])
// ---------------------------------------------------------------------------
__global__ __launch_bounds__(256) void bias_tables(const float* __restrict__ q_f32,
                                                   const float* __restrict__ emb_h,
                                                   const float* __restrict__ emb_w,
                                                   float* __restrict__ qw_abs,
                                                   float* __restrict__ qh_abs) {
    __shared__ float qs[64][36];      // rows 16B-aligned -> b128 LDS reads
    __shared__ float ehs[127][36];
    __shared__ float ews[127][36];
    const int bn = blockIdx.x >> 6;
    const int w1 = blockIdx.x & 63;
    const int tid = threadIdx.x;

    #pragma unroll
    for (int i = 0; i < 8; i++) {
        int e = i * 256 + tid;
        int h1 = e >> 5, d = e & 31;
        qs[h1][d] = q_f32[((size_t)bn * L_ + h1 * 64 + w1) * 32 + d];
    }
    #pragma unroll
    for (int i = 0; i < 16; i++) {
        int e = i * 256 + tid;
        if (e < 127 * 32) {
            int r = e >> 5, d = e & 31;
            ehs[r][d] = emb_h[e];
            ews[r][d] = emb_w[e];
        }
    }
    __syncthreads();

    const int h1 = tid & 63;
    const int mg = tid >> 6;
    for (int mm = 0; mm < 16; mm++) {
        const int m2 = mg * 16 + mm;
        const float* qrow = &qs[h1][0];
        const float* erw  = &ews[m2 - w1 + 63][0];
        const float* erh  = &ehs[m2 - h1 + 63][0];
        float sw0 = 0.f, sh0 = 0.f, sw1 = 0.f, sh1 = 0.f;
        #pragma unroll
        for (int d = 0; d < 32; d += 2) {
            sw0 = fmaf(qrow[d],     erw[d],     sw0);
            sw1 = fmaf(qrow[d + 1], erw[d + 1], sw1);
            sh0 = fmaf(qrow[d],     erh[d],     sh0);
            sh1 = fmaf(qrow[d + 1], erh[d + 1], sh1);
        }
        const size_t oidx = (size_t)bn * (64 * L_) + (size_t)m2 * L_ + w1 * 64 + h1;
        qw_abs[oidx] = sw0 + sw1;
        qh_abs[oidx] = sh0 + sh1;
    }
}

// ---------------------------------------------------------------------------
// Kernel C: MFMA flash attention, no-barrier main loop.
// Block = (bn, w1), 512 threads = 8 waves. Wave = (split s=wv>>2, qw=wv&3):
// owns 16 queries (h1 in [16qw,16qw+16)), 32 key-tiles (h2 in [32s,32s+32)).
// K/V B-frags loaded DIRECTLY from global (coalesced, L1/L2-resident),
// software-pipelined one tile ahead. Bias: qw term in 16 regs (loop-
// invariant), qh term prefetched f32x4. Online softmax with wave-vote +
// margin (full cross-lane max reduce only when a new max appears); l kept
// per-lane, reduced once at the end. P round-trips per-wave LDS (b16 writes).
// One __syncthreads total (2-split merge via LDS).
// ---------------------------------------------------------------------------
__global__ __launch_bounds__(512, 4) void attn_mfma(
    const unsigned short* __restrict__ q_bf,   // [bn][l][32]
    const unsigned short* __restrict__ k_bf,   // [bn][l][32], pre-scaled
    const unsigned short* __restrict__ vt_bf,  // [bn][32][l]
    const float* __restrict__ qw_abs,          // [bn][w2][w1][h1]
    const float* __restrict__ qh_abs,          // [bn][h2][w1][h1]
    float* __restrict__ out)
{
    __shared__ unsigned short P_lds[8][16 * 72];   // per-wave P, row 144B (16B-aligned)
    __shared__ float Obuf[64][34];                 // split-0 partial O (padded)
    __shared__ float mbuf[64], lbuf[64];

    const int bn   = blockIdx.x >> 6;
    const int w1   = blockIdx.x & 63;
    const int tid  = threadIdx.x;
    const int wv   = tid >> 6;
    const int sp   = wv >> 2;            // key split 0/1
    const int qwv  = wv & 3;
    const int lane = tid & 63;
    const int l16  = lane & 15;
    const int quad = lane >> 4;
    const int q0   = qwv * 16;

    // ---- Q A-frag: lane holds Q[q0+l16][quad*8..+8) ----
    const bfrag aq = *(const bfrag*)(q_bf +
        (((size_t)bn * L_ + (q0 + l16) * 64 + w1) * 32 + quad * 8));

    // ---- loop-invariant qw bias: [w2=sub*16+l16][q=q0+quad*4..+4) ----
    f32x4 qwreg[4];
    #pragma unroll
    for (int sub = 0; sub < 4; sub++)
        qwreg[sub] = *(const f32x4*)&qw_abs[((size_t)bn * 64 + sub * 16 + l16) * L_
                                            + w1 * 64 + q0 + quad * 4];

    const unsigned short* Kbase = k_bf  + (size_t)bn * L_ * 32;   // [l2][32]
    const unsigned short* Vbase = vt_bf + (size_t)bn * 32 * L_;   // [d][l2]
    const float* qh_base = qh_abs + (size_t)bn * 64 * L_ + w1 * 64 + q0 + quad * 4;

    const int kt0 = sp * 32, ktend = kt0 + 32;

    // ---- initial tile loads (registers; vmcnt-pipelined thereafter) ----
    bfrag kf[4], vf[4];
    #pragma unroll
    for (int sub = 0; sub < 4; sub++)
        kf[sub] = *(const bfrag*)(Kbase + (size_t)(kt0 * 64 + sub * 16 + l16) * 32 + quad * 8);
    vf[0] = *(const bfrag*)(Vbase + (size_t)l16 * L_        + kt0 * 64      + quad * 8);
    vf[1] = *(const bfrag*)(Vbase + (size_t)l16 * L_        + kt0 * 64 + 32 + quad * 8);
    vf[2] = *(const bfrag*)(Vbase + (size_t)(16 + l16) * L_ + kt0 * 64      + quad * 8);
    vf[3] = *(const bfrag*)(Vbase + (size_t)(16 + l16) * L_ + kt0 * 64 + 32 + quad * 8);
    f32x4 qh4 = *(const f32x4*)&qh_base[(size_t)kt0 * L_];

    f32x4 O0 = {0.f, 0.f, 0.f, 0.f}, O1 = {0.f, 0.f, 0.f, 0.f};
    float m_[4], l_[4];
    #pragma unroll
    for (int r = 0; r < 4; r++) { m_[r] = -INFINITY; l_[r] = 0.f; }

    unsigned short* Pw = &P_lds[wv][0];

    for (int kt = kt0; kt < ktend; kt++) {
        // ---- QK^T with bias as C-init ----
        f32x4 S[4];
        #pragma unroll
        for (int sub = 0; sub < 4; sub++)
            S[sub] = __builtin_amdgcn_mfma_f32_16x16x32_bf16(aq, kf[sub],
                                                             qh4 + qwreg[sub], 0, 0, 0);

        // ---- prefetch next K tile + qh (last use of kf/qh4 was above) ----
        const int ktn = (kt + 1 < ktend) ? kt + 1 : kt;
        #pragma unroll
        for (int sub = 0; sub < 4; sub++)
            kf[sub] = *(const bfrag*)(Kbase + (size_t)(ktn * 64 + sub * 16 + l16) * 32 + quad * 8);
        qh4 = *(const f32x4*)&qh_base[(size_t)ktn * L_];

        // ---- online softmax: vote-gated max update ----
        float mx[4];
        #pragma unroll
        for (int r = 0; r < 4; r++)
            mx[r] = fmaxf(fmaxf(S[0][r], S[1][r]), fmaxf(S[2][r], S[3][r]));
        const int need = (mx[0] > m_[0]) | (mx[1] > m_[1]) |
                         (mx[2] > m_[2]) | (mx[3] > m_[3]);
        if (__any(need)) {                       // rare after warm-up (margin)
            #pragma unroll
            for (int r = 0; r < 4; r++) {
                float v = mx[r];
                #pragma unroll
                for (int st = 1; st < 16; st <<= 1)
                    v = fmaxf(v, __shfl_xor(v, st));
                const float mn = fmaxf(m_[r], v + MARGIN);
                const float al = __expf(m_[r] - mn);   // exp(-inf)=0 first time
                m_[r] = mn;
                l_[r] *= al;
                O0[r] *= al;
                O1[r] *= al;
            }
        }

        // ---- p = exp(S - m); accumulate l per-lane; store P as bf16 ----
        #pragma unroll
        for (int sub = 0; sub < 4; sub++)
            #pragma unroll
            for (int r = 0; r < 4; r++) {
                const float p = __expf(S[sub][r] - m_[r]);
                l_[r] += p;
                Pw[(quad * 4 + r) * 72 + sub * 16 + l16] = f2bf(p);
            }

        // ---- P A-frags (cross-lane within wave; compiler emits lgkmcnt) ----
        const bfrag pa0 = *(const bfrag*)(Pw + l16 * 72 + quad * 8);        // keys 0..31
        const bfrag pa1 = *(const bfrag*)(Pw + l16 * 72 + 32 + quad * 8);   // keys 32..63

        // ---- PV ----
        O0 = __builtin_amdgcn_mfma_f32_16x16x32_bf16(pa0, vf[0], O0, 0, 0, 0);
        O0 = __builtin_amdgcn_mfma_f32_16x16x32_bf16(pa1, vf[1], O0, 0, 0, 0);
        O1 = __builtin_amdgcn_mfma_f32_16x16x32_bf16(pa0, vf[2], O1, 0, 0, 0);
        O1 = __builtin_amdgcn_mfma_f32_16x16x32_bf16(pa1, vf[3], O1, 0, 0, 0);

        // ---- prefetch next V tile (last use of vf was above) ----
        vf[0] = *(const bfrag*)(Vbase + (size_t)l16 * L_        + ktn * 64      + quad * 8);
        vf[1] = *(const bfrag*)(Vbase + (size_t)l16 * L_        + ktn * 64 + 32 + quad * 8);
        vf[2] = *(const bfrag*)(Vbase + (size_t)(16 + l16) * L_ + ktn * 64      + quad * 8);
        vf[3] = *(const bfrag*)(Vbase + (size_t)(16 + l16) * L_ + ktn * 64 + 32 + quad * 8);
    }

    // ---- reduce l across the 16 lanes of each row (once) ----
    #pragma unroll
    for (int st = 1; st < 16; st <<= 1)
        #pragma unroll
        for (int r = 0; r < 4; r++)
            l_[r] += __shfl_xor(l_[r], st);

    // ---- 2-split merge through LDS ----
    if (sp == 0) {
        #pragma unroll
        for (int r = 0; r < 4; r++) {
            const int q = q0 + quad * 4 + r;
            Obuf[q][l16]      = O0[r];
            Obuf[q][16 + l16] = O1[r];
            if (l16 == 0) { mbuf[q] = m_[r]; lbuf[q] = l_[r]; }
        }
    }
    __syncthreads();
    if (sp == 1) {
        const int head = bn & 3, bb = bn >> 2;
        #pragma unroll
        for (int r = 0; r < 4; r++) {
            const int q = q0 + quad * 4 + r;
            const float m0v = mbuf[q], l0v = lbuf[q];
            const float M  = fmaxf(m0v, m_[r]);
            const float e0 = __expf(m0v - M);
            const float e1 = __expf(m_[r] - M);
            const float inv = 1.0f / (e0 * l0v + e1 * l_[r]);
            const size_t oi = (((size_t)bb * 64 + q) * 64 + w1) * 128 + head * 32;
            out[oi + l16]      = (e0 * Obuf[q][l16]      + e1 * O0[r]) * inv;
            out[oi + 16 + l16] = (e0 * Obuf[q][16 + l16] + e1 * O1[r]) * inv;
        }
    }
}

// ---------------------------------------------------------------------------
extern "C" void kernel_launch(void* const* d_in, const int* in_sizes, int n_in,
                              void* d_out, int out_size, void* d_ws, size_t ws_size,
                              hipStream_t stream) {
    const float* x     = (const float*)d_in[0];   // [2,64,64,128]
    const float* w_qkv = (const float*)d_in[1];   // [128,384]
    const float* emb_h = (const float*)d_in[2];   // [127,32]
    const float* emb_w = (const float*)d_in[3];   // [127,32]
    float* out = (float*)d_out;

    // workspace: q_f32 (1M f), qw_abs (2M f), qh_abs (2M f), then bf16:
    // q_bf, k_bf, vt_bf (1M ush each) -> 26 MB total
    float* q_f32  = (float*)d_ws;
    float* qw_abs = q_f32 + (size_t)BN_ * L_ * KD;
    float* qh_abs = qw_abs + (size_t)BN_ * 64 * L_;
    unsigned short* q_bf  = (unsigned short*)(qh_abs + (size_t)BN_ * 64 * L_);
    unsigned short* k_bf  = q_bf + (size_t)BN_ * L_ * KD;
    unsigned short* vt_bf = k_bf + (size_t)BN_ * L_ * KD;

    qkv_gemm<<<768, 256, 0, stream>>>(x, w_qkv, q_f32, q_bf, k_bf, vt_bf);
    bias_tables<<<512, 256, 0, stream>>>(q_f32, emb_h, emb_w, qw_abs, qh_abs);
    attn_mfma<<<512, 512, 0, stream>>>(q_bf, k_bf, vt_bf, qw_abs, qh_abs, out);
}